// Round 1
// baseline (445.632 us; speedup 1.0000x reference)
//
#include <hip/hip_runtime.h>
#include <hip/hip_bf16.h>
#include <stdint.h>

#define T_STEPS 16
#define BATCH   16
#define CHANNELS 32
#define HGT 128
#define WID 128
#define HW (HGT*WID)      // 16384
#define KSEL 8192         // ascending 0-based rank of threshold = N - k

// ---------- order-preserving fp32 <-> uint32 key transform ----------
__device__ __forceinline__ uint32_t enc_key(float f) {
    uint32_t u = __float_as_uint(f);
    uint32_t mask = (uint32_t)((int32_t)u >> 31) | 0x80000000u; // neg: FFFFFFFF, pos: 80000000
    return u ^ mask;
}
__device__ __forceinline__ float dec_key(uint32_t k) {
    uint32_t mask = (k & 0x80000000u) ? 0x80000000u : 0xFFFFFFFFu;
    return __uint_as_float(k ^ mask);
}

// ---------- kernel 1: channel max pool (memory-bound streamer) ----------
__global__ __launch_bounds__(256)
void pool_max_kernel(const float* __restrict__ x, float* __restrict__ pooled) {
    int tid  = blockIdx.x * blockDim.x + threadIdx.x;   // 1,048,576 threads
    int base = tid * 4;                                 // pooled element index
    int tb   = base / HW;                               // 0..255 (t*B+b)
    int pix  = base - tb * HW;
    const float4* src = (const float4*)(x + (size_t)tb * CHANNELS * HW + pix);
    float4 m = src[0];
    #pragma unroll
    for (int c = 1; c < CHANNELS; ++c) {
        float4 v = src[(size_t)c * (HW/4)];
        m.x = fmaxf(m.x, v.x); m.y = fmaxf(m.y, v.y);
        m.z = fmaxf(m.z, v.z); m.w = fmaxf(m.w, v.w);
    }
    *(float4*)(pooled + base) = m;
}

// ---------- kernel 2: lif0 with exact radix-select top-k threshold ----------
__global__ __launch_bounds__(1024)
void lif0_kernel(const float* __restrict__ pooled, uint8_t* __restrict__ spk) {
    __shared__ uint32_t hist[16][256];   // per-wave privatized histograms
    __shared__ uint32_t s_tot[256];
    __shared__ uint32_t s_bc[2];
    const int b    = blockIdx.x;
    const int tid  = threadIdx.x;
    const int wid  = tid >> 6;
    const int lane = tid & 63;
    uint32_t* hflat = &hist[0][0];

    float m[16];
    #pragma unroll
    for (int i = 0; i < 16; ++i) m[i] = 0.0f;

    for (int t = 0; t < T_STEPS; ++t) {
        const float* p = pooled + ((size_t)t * BATCH + b) * HW;
        #pragma unroll
        for (int i = 0; i < 16; ++i) {
            int e = tid + (i << 10);
            m[i] = 0.25f * m[i] + p[e];   // 0.25*m exact -> bit-identical to ref
        }

        uint32_t prefix = 0;
        uint32_t r = KSEL;               // target ascending rank within matched set
        #pragma unroll
        for (int pass = 0; pass < 4; ++pass) {
            const int shift = 24 - (pass << 3);
            // a) clear all histograms (flat, all 1024 threads)
            #pragma unroll
            for (int j = 0; j < 4; ++j) hflat[tid * 4 + j] = 0;
            __syncthreads();
            // b) per-wave histogram of matched elements
            #pragma unroll
            for (int i = 0; i < 16; ++i) {
                uint32_t key = enc_key(m[i]);
                bool match = (pass == 0) || ((key >> (shift + 8)) == prefix);
                if (match) atomicAdd(&hist[wid][(key >> shift) & 255u], 1u);
            }
            __syncthreads();
            // c) merge 16 wave histograms -> s_tot
            if (tid < 256) {
                uint32_t tot = 0;
                #pragma unroll
                for (int w = 0; w < 16; ++w) tot += hist[w][tid];
                s_tot[tid] = tot;
            }
            __syncthreads();
            // d) wave 0: scan 256 bins, pick bin containing rank r
            if (wid == 0) {
                uint32_t c0 = s_tot[lane * 4 + 0];
                uint32_t c1 = s_tot[lane * 4 + 1];
                uint32_t c2 = s_tot[lane * 4 + 2];
                uint32_t c3 = s_tot[lane * 4 + 3];
                uint32_t lsum = c0 + c1 + c2 + c3;
                uint32_t inc = lsum;
                #pragma unroll
                for (int off = 1; off < 64; off <<= 1) {
                    uint32_t v = __shfl_up(inc, off, 64);
                    if (lane >= off) inc += v;
                }
                uint32_t c = inc - lsum;   // count in bins below lane*4
                int dsel = -1; uint32_t nr = 0;
                if (r >= c && r < c + c0) { dsel = lane * 4 + 0; nr = r - c; } c += c0;
                if (dsel < 0 && r >= c && r < c + c1) { dsel = lane * 4 + 1; nr = r - c; } c += c1;
                if (dsel < 0 && r >= c && r < c + c2) { dsel = lane * 4 + 2; nr = r - c; } c += c2;
                if (dsel < 0 && r >= c && r < c + c3) { dsel = lane * 4 + 3; nr = r - c; }
                if (dsel >= 0) { s_bc[0] = (uint32_t)dsel; s_bc[1] = nr; }
            }
            __syncthreads();
            prefix = (prefix << 8) | s_bc[0];
            r = s_bc[1];
        }

        const float thr = dec_key(prefix);   // exact k-th largest value
        uint8_t* so = spk + ((size_t)t * BATCH + b) * HW;
        #pragma unroll
        for (int i = 0; i < 16; ++i) {
            int e = tid + (i << 10);
            bool sp = (m[i] >= thr);          // float compare, same as ref
            so[e] = sp ? (uint8_t)1 : (uint8_t)0;
            m[i] = sp ? 0.0f : m[i];          // hard reset
        }
        __syncthreads();
    }
}

// ---------- kernel 3: fused 7x7 conv (cross-correlation) + lif1 ----------
__global__ __launch_bounds__(256)
void conv_lif1_kernel(const uint8_t* __restrict__ spk, const float* __restrict__ wconv,
                      float* __restrict__ out_spike, float* __restrict__ out_mem) {
    __shared__ float tile[14][134];   // 8-row stripe + 3 halo each side; 3-col pad each side
    __shared__ float sw[49];
    const int bidx   = blockIdx.x;
    const int b      = bidx >> 4;
    const int stripe = bidx & 15;
    const int r0     = stripe * 8;
    const int tid    = threadIdx.x;
    if (tid < 49) sw[tid] = wconv[tid];

    float mem[4] = {0.0f, 0.0f, 0.0f, 0.0f};

    for (int t = 0; t < T_STEPS; ++t) {
        __syncthreads();   // tile reuse guard (and sw visibility at t=0)
        const uint8_t* sp = spk + ((size_t)t * BATCH + b) * HW;
        for (int k = tid; k < 14 * 134; k += 256) {
            int row = k / 134;
            int col = k - row * 134;
            int gr = r0 - 3 + row;
            int gc = col - 3;
            float v = 0.0f;
            if (gr >= 0 && gr < HGT && gc >= 0 && gc < WID)
                v = (float)sp[gr * WID + gc];
            tile[row][col] = v;
        }
        __syncthreads();
        const size_t obase = ((size_t)t * BATCH + b) * HW;
        #pragma unroll
        for (int i = 0; i < 4; ++i) {
            int pix = tid + (i << 8);
            int lr = pix >> 7;      // 0..7
            int lc = pix & 127;
            float acc = 0.0f;
            #pragma unroll
            for (int dy = 0; dy < 7; ++dy)
                #pragma unroll
                for (int dx = 0; dx < 7; ++dx)
                    acc = fmaf(tile[lr + dy][lc + dx], sw[dy * 7 + dx], acc);
            float mm = 0.25f * mem[i] + acc;
            float sp2 = (mm > 1.0f) ? 1.0f : 0.0f;
            size_t o = obase + (size_t)(r0 + lr) * WID + lc;
            out_spike[o] = sp2;
            out_mem[o]   = mm;
            mem[i] = mm - sp2;      // soft reset
        }
    }
}

extern "C" void kernel_launch(void* const* d_in, const int* in_sizes, int n_in,
                              void* d_out, int out_size, void* d_ws, size_t ws_size,
                              hipStream_t stream) {
    const float* x     = (const float*)d_in[0];
    const float* wconv = (const float*)d_in[1];
    float* out = (float*)d_out;

    const size_t n_pooled = (size_t)T_STEPS * BATCH * HW;     // 4,194,304
    float*   pooled = (float*)d_ws;
    uint8_t* spk    = (uint8_t*)d_ws + n_pooled * sizeof(float);

    // 1) channel max pool: 1,048,576 float4 threads
    pool_max_kernel<<<4096, 256, 0, stream>>>(x, pooled);
    // 2) lif0 with exact top-k threshold: one block per sample
    lif0_kernel<<<BATCH, 1024, 0, stream>>>(pooled, spk);
    // 3) fused conv + lif1: one block per (b, 8-row stripe)
    conv_lif1_kernel<<<BATCH * 16, 256, 0, stream>>>(spk, wconv, out, out + n_pooled);
}

// Round 2
// 302.347 us; speedup vs baseline: 1.4739x; 1.4739x over previous
//
#include <hip/hip_runtime.h>
#include <hip/hip_bf16.h>
#include <stdint.h>

#define T_STEPS 16
#define BATCH   16
#define CHANNELS 32
#define HGT 128
#define WID 128
#define HW (HGT*WID)      // 16384
#define KSEL 8192         // ascending 0-based rank of threshold = N - k
#define CAP 1024          // max candidates for exact rank-select

// ---------- kernel 1: channel max pool (memory-bound streamer) ----------
__global__ __launch_bounds__(256)
void pool_max_kernel(const float* __restrict__ x, float* __restrict__ pooled) {
    int tid  = blockIdx.x * blockDim.x + threadIdx.x;   // 1,048,576 threads
    int base = tid * 4;                                 // pooled element index
    int tb   = base >> 14;                              // /HW
    int pix  = base & (HW - 1);
    const float4* src = (const float4*)(x + (size_t)tb * CHANNELS * HW + pix);
    float4 m = src[0];
    #pragma unroll
    for (int c = 1; c < CHANNELS; ++c) {
        float4 v = src[(size_t)c * (HW/4)];
        m.x = fmaxf(m.x, v.x); m.y = fmaxf(m.y, v.y);
        m.z = fmaxf(m.z, v.z); m.w = fmaxf(m.w, v.w);
    }
    *(float4*)(pooled + base) = m;
}

// ---------- kernel 2: lif0 with exact linear-histogram select ----------
__global__ __launch_bounds__(1024)
void lif0_kernel(const float* __restrict__ pooled, uint8_t* __restrict__ spk) {
    __shared__ uint32_t hist[16][260];   // per-wave rows, padded -> per-wave bank offset
    __shared__ float    col[CAP];
    __shared__ uint32_t s_sel[4];        // jsel, r_new, cnt_new, collect-counter
    __shared__ float    s_thr;

    const int b    = blockIdx.x;
    const int tid  = threadIdx.x;
    const int wid  = tid >> 6;
    const int lane = tid & 63;
    uint32_t* hflat = &hist[0][0];

    float m[16];
    #pragma unroll
    for (int i = 0; i < 16; ++i) m[i] = 0.0f;

    for (int t = 0; t < T_STEPS; ++t) {
        // ---- integrate: mem = 0.25*mem + x  (bit-identical to ref) ----
        const float4* p4 = (const float4*)(pooled + ((size_t)t * BATCH + b) * HW);
        #pragma unroll
        for (int i = 0; i < 4; ++i) {
            float4 v = p4[i * 1024 + tid];
            m[i*4+0] = 0.25f * m[i*4+0] + v.x;
            m[i*4+1] = 0.25f * m[i*4+1] + v.y;
            m[i*4+2] = 0.25f * m[i*4+2] + v.z;
            m[i*4+3] = 0.25f * m[i*4+3] + v.w;
        }

        // ---- exact select of ascending-rank KSEL via linear histogram ----
        uint32_t amask = 0xFFFFu;        // alive (candidate) elements
        float    rlo   = -16.0f;
        float    scale = 8.0f;           // 256 bins over width 32
        uint32_t r     = KSEL;           // target rank within alive set
        uint32_t cnt   = HW;
        int      iter  = 0;
        for (;;) {
            // clear histograms (16*260 = 4160 words)
            #pragma unroll
            for (int j = 0; j < 5; ++j) {
                int idx = tid + (j << 10);
                if (idx < 16 * 260) hflat[idx] = 0;
            }
            __syncthreads();
            // histogram alive elements (linear value bins -> spread, few conflicts)
            #pragma unroll
            for (int i = 0; i < 16; ++i) {
                if (amask & (1u << i)) {
                    int bn = (int)((m[i] - rlo) * scale);
                    bn = min(max(bn, 0), 255);
                    atomicAdd(&hist[wid][bn], 1u);
                }
            }
            __syncthreads();
            // wave 0: merge+scan 256 bins, pick bin containing rank r
            if (wid == 0) {
                uint32_t c[4], lsum = 0;
                #pragma unroll
                for (int q = 0; q < 4; ++q) {
                    int bn = lane * 4 + q;
                    uint32_t s = 0;
                    #pragma unroll
                    for (int w = 0; w < 16; ++w) s += hist[w][bn];
                    c[q] = s; lsum += s;
                }
                uint32_t inc = lsum;
                #pragma unroll
                for (int off = 1; off < 64; off <<= 1) {
                    uint32_t v = __shfl_up(inc, off, 64);
                    if (lane >= off) inc += v;
                }
                uint32_t acc = inc - lsum;   // count below lane*4
                int dsel = -1; uint32_t nr = 0, nc = 0;
                #pragma unroll
                for (int q = 0; q < 4; ++q) {
                    if (dsel < 0 && r >= acc && r < acc + c[q]) {
                        dsel = lane * 4 + q; nr = r - acc; nc = c[q];
                    }
                    acc += c[q];
                }
                if (dsel >= 0) { s_sel[0] = (uint32_t)dsel; s_sel[1] = nr; s_sel[2] = nc; }
                if (tid == 0) s_sel[3] = 0;  // reset collect counter
            }
            __syncthreads();
            const int jsel = (int)s_sel[0];
            r   = s_sel[1];
            cnt = s_sel[2];
            // keep only elements in the selected bin (identical bin computation)
            #pragma unroll
            for (int i = 0; i < 16; ++i) {
                if (amask & (1u << i)) {
                    int bn = (int)((m[i] - rlo) * scale);
                    bn = min(max(bn, 0), 255);
                    if (bn != jsel) amask &= ~(1u << i);
                }
            }
            rlo   = rlo + (float)jsel / scale;
            scale = scale * 256.0f;
            if (cnt <= CAP || ++iter >= 6) break;
        }

        // ---- collect candidates: wave scan + 1 atomic per wave ----
        {
            uint32_t myc  = (uint32_t)__popc((int)amask);
            uint32_t incl = myc;
            #pragma unroll
            for (int off = 1; off < 64; off <<= 1) {
                uint32_t v = __shfl_up(incl, off, 64);
                if (lane >= off) incl += v;
            }
            uint32_t wtot = __shfl(incl, 63, 64);
            uint32_t base = 0;
            if (lane == 63) base = atomicAdd(&s_sel[3], wtot);
            base = __shfl(base, 63, 64);
            uint32_t off = base + incl - myc;
            #pragma unroll
            for (int i = 0; i < 16; ++i) {
                if (amask & (1u << i)) {
                    if (off < CAP) col[off] = m[i];
                    ++off;
                }
            }
        }
        __syncthreads();
        // ---- exact rank-select among candidates (float compares) ----
        {
            uint32_t ncol = min(cnt, (uint32_t)CAP);
            for (uint32_t j = tid; j < ncol; j += 1024) {
                float v = col[j];
                uint32_t less = 0, leq = 0;
                for (uint32_t i = 0; i < ncol; ++i) {
                    float u = col[i];
                    less += (u < v);
                    leq  += (u <= v);
                }
                if (less <= r && r < leq) s_thr = v;   // unique value, identical bits
            }
        }
        __syncthreads();
        const float thr = s_thr;

        // ---- spikes + hard reset ----
        uchar4* so4 = (uchar4*)(spk + ((size_t)t * BATCH + b) * HW);
        #pragma unroll
        for (int i = 0; i < 4; ++i) {
            uchar4 s4;
            s4.x = (m[i*4+0] >= thr) ? 1 : 0;
            s4.y = (m[i*4+1] >= thr) ? 1 : 0;
            s4.z = (m[i*4+2] >= thr) ? 1 : 0;
            s4.w = (m[i*4+3] >= thr) ? 1 : 0;
            if (s4.x) m[i*4+0] = 0.0f;
            if (s4.y) m[i*4+1] = 0.0f;
            if (s4.z) m[i*4+2] = 0.0f;
            if (s4.w) m[i*4+3] = 0.0f;
            so4[i * 1024 + tid] = s4;
        }
        __syncthreads();   // protect LDS reuse next t
    }
}

// ---------- kernel 3: fused 7x7 conv (cross-correlation) + lif1 ----------
__global__ __launch_bounds__(256)
void conv_lif1_kernel(const uint8_t* __restrict__ spk, const float* __restrict__ wconv,
                      float* __restrict__ out_spike, float* __restrict__ out_mem) {
    __shared__ float tile[8][136];   // 2-row stripe + 3 halo each side; col-padded
    __shared__ float sw[49];
    const int bidx   = blockIdx.x;   // 0..1023
    const int b      = bidx >> 6;
    const int stripe = bidx & 63;    // 64 stripes of 2 rows
    const int r0     = stripe * 2;
    const int tid    = threadIdx.x;
    const int lr     = tid >> 7;     // 0..1
    const int lc     = tid & 127;
    if (tid < 49) sw[tid] = wconv[tid];

    float mem = 0.0f;

    for (int t = 0; t < T_STEPS; ++t) {
        __syncthreads();   // tile reuse guard (and sw visibility at t=0)
        const uint8_t* sp = spk + ((size_t)t * BATCH + b) * HW;
        for (int k = tid; k < 8 * 134; k += 256) {
            int row = k / 134;
            int colp = k - row * 134;
            int gr = r0 - 3 + row;
            int gc = colp - 3;
            float v = 0.0f;
            if (gr >= 0 && gr < HGT && gc >= 0 && gc < WID)
                v = (float)sp[gr * WID + gc];
            tile[row][colp] = v;
        }
        __syncthreads();
        float acc = 0.0f;
        #pragma unroll
        for (int dy = 0; dy < 7; ++dy)
            #pragma unroll
            for (int dx = 0; dx < 7; ++dx)
                acc = fmaf(tile[lr + dy][lc + dx], sw[dy * 7 + dx], acc);
        float mm  = 0.25f * mem + acc;
        float sp2 = (mm > 1.0f) ? 1.0f : 0.0f;
        size_t o = ((size_t)t * BATCH + b) * HW + (size_t)(r0 + lr) * WID + lc;
        out_spike[o] = sp2;
        out_mem[o]   = mm;
        mem = mm - sp2;      // soft reset
    }
}

extern "C" void kernel_launch(void* const* d_in, const int* in_sizes, int n_in,
                              void* d_out, int out_size, void* d_ws, size_t ws_size,
                              hipStream_t stream) {
    const float* x     = (const float*)d_in[0];
    const float* wconv = (const float*)d_in[1];
    float* out = (float*)d_out;

    const size_t n_pooled = (size_t)T_STEPS * BATCH * HW;     // 4,194,304
    float*   pooled = (float*)d_ws;
    uint8_t* spk    = (uint8_t*)d_ws + n_pooled * sizeof(float);

    pool_max_kernel<<<4096, 256, 0, stream>>>(x, pooled);
    lif0_kernel<<<BATCH, 1024, 0, stream>>>(pooled, spk);
    conv_lif1_kernel<<<BATCH * 64, 256, 0, stream>>>(spk, wconv, out, out + n_pooled);
}

// Round 4
// 275.556 us; speedup vs baseline: 1.6172x; 1.0972x over previous
//
#include <hip/hip_runtime.h>
#include <hip/hip_bf16.h>
#include <stdint.h>

#define T_STEPS 16
#define BATCH   16
#define CHANNELS 32
#define HGT 128
#define WID 128
#define HW (HGT*WID)      // 16384
#define KSEL 8192         // ascending 0-based rank of threshold = N - k
#define CAP 1024          // candidate buffer size (safety)
#define SMALL 64          // stop narrowing when candidate set <= SMALL

typedef float vfloat4 __attribute__((ext_vector_type(4)));

// ---------- kernel 1: channel max pool (memory-bound streamer) ----------
__global__ __launch_bounds__(256)
void pool_max_kernel(const float* __restrict__ x, float* __restrict__ pooled) {
    int tid  = blockIdx.x * blockDim.x + threadIdx.x;   // 1,048,576 threads
    int base = tid * 4;                                 // pooled element index
    int tb   = base >> 14;                              // /HW
    int pix  = base & (HW - 1);
    const vfloat4* src = (const vfloat4*)(x + (size_t)tb * CHANNELS * HW + pix);
    vfloat4 m = __builtin_nontemporal_load(src);
    #pragma unroll
    for (int c = 1; c < CHANNELS; ++c) {
        vfloat4 v = __builtin_nontemporal_load(src + (size_t)c * (HW/4));
        m.x = fmaxf(m.x, v.x); m.y = fmaxf(m.y, v.y);
        m.z = fmaxf(m.z, v.z); m.w = fmaxf(m.w, v.w);
    }
    *(vfloat4*)(pooled + base) = m;
}

// ---------- kernel 2: lif0 with exact linear-histogram select ----------
__global__ __launch_bounds__(1024)
void lif0_kernel(const float* __restrict__ pooled, uint8_t* __restrict__ spk) {
    __shared__ uint32_t hist[16][260];   // per-wave rows, padded
    __shared__ uint32_t s_tot[256];      // merged histogram
    __shared__ float    col[CAP];
    __shared__ uint32_t s_sel[4];        // jsel, r_new, cnt_new, collect-counter
    __shared__ float    s_thr;

    const int b    = blockIdx.x;
    const int tid  = threadIdx.x;
    const int wid  = tid >> 6;
    const int lane = tid & 63;
    uint32_t* hflat = &hist[0][0];

    float m[16];
    #pragma unroll
    for (int i = 0; i < 16; ++i) m[i] = 0.0f;

    for (int t = 0; t < T_STEPS; ++t) {
        // ---- integrate: mem = 0.25*mem + x  (bit-identical to ref) ----
        const float4* p4 = (const float4*)(pooled + ((size_t)t * BATCH + b) * HW);
        #pragma unroll
        for (int i = 0; i < 4; ++i) {
            float4 v = p4[i * 1024 + tid];
            m[i*4+0] = 0.25f * m[i*4+0] + v.x;
            m[i*4+1] = 0.25f * m[i*4+1] + v.y;
            m[i*4+2] = 0.25f * m[i*4+2] + v.z;
            m[i*4+3] = 0.25f * m[i*4+3] + v.w;
        }

        // ---- exact select of ascending-rank KSEL via linear histogram ----
        uint32_t amask = 0xFFFFu;        // alive (candidate) elements
        float    rlo   = 0.0f;           // values are max-of-32-normals: ~[0.5,4.5]
        float    scale = 32.0f;          // 256 bins over [0,8): width 1/32
        uint32_t r     = KSEL;           // target rank within alive set
        uint32_t cnt   = HW;
        int      iter  = 0;
        for (;;) {
            // clear histograms (16*260 = 4160 words)
            #pragma unroll
            for (int j = 0; j < 5; ++j) {
                int idx = tid + (j << 10);
                if (idx < 16 * 260) hflat[idx] = 0;
            }
            __syncthreads();
            // per-wave histogram of alive elements (linear value bins)
            #pragma unroll
            for (int i = 0; i < 16; ++i) {
                if (amask & (1u << i)) {
                    int bn = (int)((m[i] - rlo) * scale);
                    bn = min(max(bn, 0), 255);
                    atomicAdd(&hist[wid][bn], 1u);
                }
            }
            __syncthreads();
            // parallel merge: 256 threads x 16 reads (was: wave0 x 64 reads)
            if (tid < 256) {
                uint32_t s = 0;
                #pragma unroll
                for (int w = 0; w < 16; ++w) s += hist[w][tid];
                s_tot[tid] = s;
            }
            __syncthreads();
            // wave 0: scan 256 bins (4/lane), pick bin containing rank r
            if (wid == 0) {
                uint32_t c[4], lsum = 0;
                #pragma unroll
                for (int q = 0; q < 4; ++q) { c[q] = s_tot[lane * 4 + q]; lsum += c[q]; }
                uint32_t inc = lsum;
                #pragma unroll
                for (int off = 1; off < 64; off <<= 1) {
                    uint32_t v = __shfl_up(inc, off, 64);
                    if (lane >= off) inc += v;
                }
                uint32_t acc = inc - lsum;   // count below lane*4
                int dsel = -1; uint32_t nr = 0, nc = 0;
                #pragma unroll
                for (int q = 0; q < 4; ++q) {
                    if (dsel < 0 && r >= acc && r < acc + c[q]) {
                        dsel = lane * 4 + q; nr = r - acc; nc = c[q];
                    }
                    acc += c[q];
                }
                if (dsel >= 0) { s_sel[0] = (uint32_t)dsel; s_sel[1] = nr; s_sel[2] = nc; }
                if (tid == 0) s_sel[3] = 0;  // reset collect counter
            }
            __syncthreads();
            const int jsel = (int)s_sel[0];
            r   = s_sel[1];
            cnt = s_sel[2];
            // keep only elements in the selected bin (identical bin computation)
            #pragma unroll
            for (int i = 0; i < 16; ++i) {
                if (amask & (1u << i)) {
                    int bn = (int)((m[i] - rlo) * scale);
                    bn = min(max(bn, 0), 255);
                    if (bn != jsel) amask &= ~(1u << i);
                }
            }
            rlo   = rlo + (float)jsel / scale;
            scale = scale * 256.0f;
            if (cnt <= SMALL || ++iter >= 6) break;
        }

        // ---- collect candidates: wave scan + 1 atomic per wave ----
        {
            uint32_t myc  = (uint32_t)__popc((int)amask);
            uint32_t incl = myc;
            #pragma unroll
            for (int off = 1; off < 64; off <<= 1) {
                uint32_t v = __shfl_up(incl, off, 64);
                if (lane >= off) incl += v;
            }
            uint32_t wtot = __shfl(incl, 63, 64);
            uint32_t base = 0;
            if (lane == 63) base = atomicAdd(&s_sel[3], wtot);
            base = __shfl(base, 63, 64);
            uint32_t off = base + incl - myc;
            #pragma unroll
            for (int i = 0; i < 16; ++i) {
                if (amask & (1u << i)) {
                    if (off < CAP) col[off] = m[i];
                    ++off;
                }
            }
        }
        __syncthreads();
        // ---- exact rank-select among candidates (float compares) ----
        {
            uint32_t ncol = min(cnt, (uint32_t)CAP);
            for (uint32_t j = tid; j < ncol; j += 1024) {
                float v = col[j];
                uint32_t less = 0, leq = 0;
                for (uint32_t i = 0; i < ncol; ++i) {
                    float u = col[i];
                    less += (u < v);
                    leq  += (u <= v);
                }
                if (less <= r && r < leq) s_thr = v;   // k-th largest, exact bits
            }
        }
        __syncthreads();
        const float thr = s_thr;

        // ---- spikes + hard reset ----
        uchar4* so4 = (uchar4*)(spk + ((size_t)t * BATCH + b) * HW);
        #pragma unroll
        for (int i = 0; i < 4; ++i) {
            uchar4 s4;
            s4.x = (m[i*4+0] >= thr) ? 1 : 0;
            s4.y = (m[i*4+1] >= thr) ? 1 : 0;
            s4.z = (m[i*4+2] >= thr) ? 1 : 0;
            s4.w = (m[i*4+3] >= thr) ? 1 : 0;
            if (s4.x) m[i*4+0] = 0.0f;
            if (s4.y) m[i*4+1] = 0.0f;
            if (s4.z) m[i*4+2] = 0.0f;
            if (s4.w) m[i*4+3] = 0.0f;
            so4[i * 1024 + tid] = s4;
        }
        __syncthreads();   // protect LDS reuse next t
    }
}

// ---------- kernel 3: fused 7x7 conv (cross-correlation) + lif1 ----------
__global__ __launch_bounds__(256)
void conv_lif1_kernel(const uint8_t* __restrict__ spk, const float* __restrict__ wconv,
                      float* __restrict__ out_spike, float* __restrict__ out_mem) {
    __shared__ float tile[8][136];   // 2-row stripe + 3 halo each side; col-padded
    __shared__ float sw[49];
    const int bidx   = blockIdx.x;   // 0..1023
    const int b      = bidx >> 6;
    const int stripe = bidx & 63;    // 64 stripes of 2 rows
    const int r0     = stripe * 2;
    const int tid    = threadIdx.x;
    const int lr     = tid >> 7;     // 0..1
    const int lc     = tid & 127;
    if (tid < 49) sw[tid] = wconv[tid];

    float mem = 0.0f;

    for (int t = 0; t < T_STEPS; ++t) {
        __syncthreads();   // tile reuse guard (and sw visibility at t=0)
        const uint8_t* sp = spk + ((size_t)t * BATCH + b) * HW;
        for (int k = tid; k < 8 * 134; k += 256) {
            int row = k / 134;
            int colp = k - row * 134;
            int gr = r0 - 3 + row;
            int gc = colp - 3;
            float v = 0.0f;
            if (gr >= 0 && gr < HGT && gc >= 0 && gc < WID)
                v = (float)sp[gr * WID + gc];
            tile[row][colp] = v;
        }
        __syncthreads();
        float acc = 0.0f;
        #pragma unroll
        for (int dy = 0; dy < 7; ++dy)
            #pragma unroll
            for (int dx = 0; dx < 7; ++dx)
                acc = fmaf(tile[lr + dy][lc + dx], sw[dy * 7 + dx], acc);
        float mm  = 0.25f * mem + acc;
        float sp2 = (mm > 1.0f) ? 1.0f : 0.0f;
        size_t o = ((size_t)t * BATCH + b) * HW + (size_t)(r0 + lr) * WID + lc;
        out_spike[o] = sp2;
        out_mem[o]   = mm;
        mem = mm - sp2;      // soft reset
    }
}

extern "C" void kernel_launch(void* const* d_in, const int* in_sizes, int n_in,
                              void* d_out, int out_size, void* d_ws, size_t ws_size,
                              hipStream_t stream) {
    const float* x     = (const float*)d_in[0];
    const float* wconv = (const float*)d_in[1];
    float* out = (float*)d_out;

    const size_t n_pooled = (size_t)T_STEPS * BATCH * HW;     // 4,194,304
    float*   pooled = (float*)d_ws;
    uint8_t* spk    = (uint8_t*)d_ws + n_pooled * sizeof(float);

    pool_max_kernel<<<4096, 256, 0, stream>>>(x, pooled);
    lif0_kernel<<<BATCH, 1024, 0, stream>>>(pooled, spk);
    conv_lif1_kernel<<<BATCH * 64, 256, 0, stream>>>(spk, wconv, out, out + n_pooled);
}